// Round 16
// baseline (88.886 us; speedup 1.0000x reference)
//
#include <hip/hip_runtime.h>
#include <hip/hip_bf16.h>
#include <math.h>

typedef __attribute__((ext_vector_type(4)))  float f32x4;
typedef __attribute__((ext_vector_type(8)))  short bf16x8;
typedef __attribute__((ext_vector_type(4)))  int   i32x4;

#define NB 2
#define NH 12
#define NS 2048
#define ND 64
#define NKER 9
#define BH (NB*NH)
#define BHS (NB*NH*NS)
#define NT (NS/64)        // 32 tiles of 64 keys

using bf16 = __hip_bfloat16;

__device__ __forceinline__ f32x4 mfma16(bf16x8 a, bf16x8 b, f32x4 c) {
  return __builtin_amdgcn_mfma_f32_16x16x32_bf16(a, b, c, 0, 0, 0);
}

// RNE float->bf16 (finite inputs).
__device__ __forceinline__ unsigned short bf16rne(float f) {
  unsigned u = __builtin_bit_cast(unsigned, f);
  u += 0x7FFFu + ((u >> 16) & 1u);
  return (unsigned short)(u >> 16);
}

// ---------------------------------------------------------------------------
// prep: per (bh, 64-seq tile): depthwise conv -> out, masked V^T bf16 -> Vmt,
// and L2-normalized K -> Kn. One pass over K/V.
// ---------------------------------------------------------------------------
__global__ __launch_bounds__(256) void prep(
    const float* __restrict__ K, const float* __restrict__ V,
    const float* __restrict__ mask, const float* __restrict__ cw,
    float* __restrict__ out, bf16* __restrict__ Kn, bf16* __restrict__ Vmt) {
  __shared__ float tile[72][68];
  __shared__ float wsm[NKER];
  int bh = blockIdx.y, b = bh / NH, h = bh % NH;
  int s0 = blockIdx.x * 64;
  int tid = threadIdx.x;
  if (tid < NKER) wsm[tid] = cw[h * NKER + tid];

  int r  = tid >> 2;
  int c0 = (tid & 3) * 16;

  // --- K-normalize rows
  {
    const float* Kr = K + ((size_t)bh * NS + s0 + r) * ND + c0;
    float v[16]; float ss = 0.f;
    #pragma unroll
    for (int j = 0; j < 16; ++j) { v[j] = Kr[j]; ss += v[j] * v[j]; }
    ss += __shfl_xor(ss, 1); ss += __shfl_xor(ss, 2);
    float sc = rsqrtf(fmaxf(ss, 1e-24f));
    bf16x8 o0, o1;
    #pragma unroll
    for (int j = 0; j < 8; ++j) {
      o0[j] = (short)bf16rne(v[j] * sc);
      o1[j] = (short)bf16rne(v[8 + j] * sc);
    }
    bf16* dst = Kn + ((size_t)bh * NS + s0 + r) * ND + c0;
    *(bf16x8*)dst = o0; *(bf16x8*)(dst + 8) = o1;
  }

  // --- masked V halo tile
  #pragma unroll
  for (int pass = 0; pass < 2; ++pass) {
    int rr = r + pass * 64;
    if (pass == 0 || tid < 32) {
      int gs = s0 - NKER / 2 + rr;
      bool ok = (gs >= 0 && gs < NS);
      float m = ok ? mask[b * NS + gs] : 0.f;
      #pragma unroll
      for (int j = 0; j < 16; ++j)
        tile[rr][c0 + j] = ok ? V[((size_t)bh * NS + gs) * ND + c0 + j] * m : 0.f;
    }
  }
  __syncthreads();

  // --- conv
  {
    float acc[16];
    #pragma unroll
    for (int j = 0; j < 16; ++j) acc[j] = 0.f;
    #pragma unroll
    for (int k = 0; k < NKER; ++k) {
      float w = wsm[k];
      #pragma unroll
      for (int j = 0; j < 16; ++j) acc[j] += tile[r + k][c0 + j] * w;
    }
    float* dst = out + ((size_t)bh * NS + s0 + r) * ND + c0;
    #pragma unroll
    for (int j = 0; j < 16; ++j) dst[j] = acc[j];
  }
  // --- V^T (masked, bf16)
  {
    bf16x8 o0, o1;
    #pragma unroll
    for (int j = 0; j < 8; ++j) {
      o0[j] = (short)bf16rne(tile[NKER / 2 + c0 + j][r]);
      o1[j] = (short)bf16rne(tile[NKER / 2 + c0 + 8 + j][r]);
    }
    bf16* dst = Vmt + (size_t)bh * ND * NS + (size_t)r * NS + s0 + c0;
    *(bf16x8*)dst = o0; *(bf16x8*)(dst + 8) = o1;
  }
}

// ---------------------------------------------------------------------------
// Fused YOSO attention -- R5 skeleton + later wins. Block = 64 q x 64-key
// tiles; 8 waves = 4 qsub (16q) x 2 kh (32k). 16x16x32 MFMA (short chains,
// 4-reg accs -> ~56 total regs, 8 waves/SIMD cap). Reg-staged double-buffered
// K/V (2 x 16 KB), ONE barrier/tile. P via per-wave LDS (2 KB).
// Transform: DEG-4 series (R10-R14-proven: bias-safe for the 2048-key sum;
// deg-2's one-signed truncation cost R15 4x absmax): t = 1 - sqrt(u)*g(u),
// g = (1/pi)acos(1-u)/sqrt(u), u = 1-x in [0,2]; w = t^8.
// Q normalized in prologue from f32. XCD-aware 1D decode. Epilogue:
// kh-combine via LDS. LDS tiles swizzled byte ^= (row&7)<<4.
// ---------------------------------------------------------------------------
__global__ __launch_bounds__(512) void yoso_attn(
    const float* __restrict__ Q, const bf16* __restrict__ Kn,
    const bf16* __restrict__ Vmt, const float* __restrict__ mask,
    float* __restrict__ out) {
  __shared__ __align__(16) char lds[48 * 1024];
  // buf b at b*16384: K [64 keys][128B], V^T [64 d][128B] at +8192.
  // P per wave 2 KB at 32768; epilogue cmb overlays P region.

  int tid  = threadIdx.x;
  int wave = tid >> 6;
  int lane = tid & 63;
  int lo   = lane & 15;
  int hi   = lane >> 4;
  int qsub = wave >> 1;           // 0..3 : 16-q subtile
  int kh   = wave & 1;            // 0..1 : 32-key half

  // XCD-aware decode: bx&7 = XCD; each XCD serves bh in {x, x+8, x+16}.
  int bx  = blockIdx.x;
  int idx = bx >> 3;                 // 0..95
  int bh  = (bx & 7) + 8 * (idx >> 5);
  int qg  = idx & 31;
  int b   = bh / NH;
  int q0  = qg * 64;

  const bf16* Kbh = Kn  + (size_t)bh * NS * ND;
  const bf16* Vbh = Vmt + (size_t)bh * ND * NS;

  // ---- Q load (f32) + L2-normalize + A-fragments (row=lo, k-octet=hi)
  bf16x8 aq0, aq1;
  {
    int qrow = q0 + qsub * 16 + lo;
    const float* Qr = Q + ((size_t)bh * NS + qrow) * ND;
    f32x4 a0 = *(const f32x4*)(Qr + hi * 8);
    f32x4 a1 = *(const f32x4*)(Qr + hi * 8 + 4);
    f32x4 a2 = *(const f32x4*)(Qr + 32 + hi * 8);
    f32x4 a3 = *(const f32x4*)(Qr + 32 + hi * 8 + 4);
    float ss = 0.f;
    #pragma unroll
    for (int j = 0; j < 4; ++j)
      ss += a0[j] * a0[j] + a1[j] * a1[j] + a2[j] * a2[j] + a3[j] * a3[j];
    ss += __shfl_xor(ss, 16);
    ss += __shfl_xor(ss, 32);   // row lanes: {lo, lo+16, lo+32, lo+48}
    float sc = rsqrtf(fmaxf(ss, 1e-24f));
    #pragma unroll
    for (int j = 0; j < 4; ++j) {
      aq0[j]     = (short)bf16rne(a0[j] * sc);
      aq0[4 + j] = (short)bf16rne(a1[j] * sc);
      aq1[j]     = (short)bf16rne(a2[j] * sc);
      aq1[4 + j] = (short)bf16rne(a3[j] * sc);
    }
  }

  f32x4 xacc[4];
  #pragma unroll
  for (int i = 0; i < 4; ++i) xacc[i] = (f32x4){0.f, 0.f, 0.f, 0.f};

  // ---- staging: 512 threads, 1 K-chunk + 1 V-chunk (16B) each per tile.
  int kr = tid >> 3, kc = (tid & 7) * 16;
  int kd = kr * 128 + (kc ^ ((kr & 7) << 4));
  int vd = 8192 + kd;
  const char* KsA = (const char*)Kbh + (size_t)kr * 128 + kc;       // +8192/tile
  const char* VsA = (const char*)Vbh + (size_t)kr * (NS * 2) + kc;  // +128/tile

  // prologue: stage tile 0 into buffer 0
  *(i32x4*)(lds + kd) = *(const i32x4*)KsA;
  *(i32x4*)(lds + vd) = *(const i32x4*)VsA;

  char* pw = lds + 32768 + wave * 2048;
  i32x4 kA, vA;

  for (int kt = 0; kt < NT; ++kt) {
    __syncthreads();   // staged writes for tile kt visible
    if (kt < NT - 1) { // issue next-tile loads; fly under the whole compute
      kA = *(const i32x4*)(KsA + (size_t)(kt + 1) * 8192);
      vA = *(const i32x4*)(VsA + (size_t)(kt + 1) * 128);
    }
    char* kb = lds + (kt & 1) * 16384;
    char* vb = kb + 8192;

    // QK^T on this wave's 2 local 16-key groups, transform, store P.
    #pragma unroll
    for (int cgl = 0; cgl < 2; ++cgl) {
      int cg   = kh * 2 + cgl;
      f32x4 s  = (f32x4){0.f, 0.f, 0.f, 0.f};
      int krow = cg * 16 + lo;
      const char* kbase = kb + krow * 128;
      int sw = (krow & 7) << 4;
      bf16x8 bk0 = *(const bf16x8*)(kbase + ((hi * 16) ^ sw));
      bf16x8 bk1 = *(const bf16x8*)(kbase + ((64 + hi * 16) ^ sw));
      s = mfma16(aq0, bk0, s);
      s = mfma16(aq1, bk1, s);
      #pragma unroll
      for (int r = 0; r < 4; ++r) {
        float x  = fminf(s[r], 0.999999f);
        float u  = 1.0f - x;
        float sq = __builtin_amdgcn_sqrtf(u);
        float gg = fmaf(fmaf(fmaf(fmaf(8.54787e-4f, u, 2.512043e-3f), u,
                                  8.440465e-3f), u, 3.7513178e-2f), u,
                        0.45015816f);             // (1/pi)acos(1-u)/sqrt(u)
        float t1 = fmaf(-sq, gg, 1.0f);           // 1 - acos(x)/pi
        float t2 = t1 * t1, t4 = t2 * t2, w = t4 * t4;
        int prow = hi * 4 + r;
        int pcol = cgl * 16 + lo;   // local key col (global kh*32 + pcol)
        *(short*)(pw + prow * 128 + ((pcol * 2) ^ ((prow & 7) << 4))) =
            (short)bf16rne(w);
      }
    }

    // PV over this wave's 32 keys (one K=32 MFMA step).
    {
      const char* pbase = pw + lo * 128;
      bf16x8 ap = *(const bf16x8*)(pbase + ((hi * 16) ^ ((lo & 7) << 4)));
      #pragma unroll
      for (int dg = 0; dg < 4; ++dg) {
        int drow = dg * 16 + lo;
        const char* vbase = vb + drow * 128;
        bf16x8 bv = *(const bf16x8*)(vbase + ((kh * 64 + hi * 16) ^ ((drow & 7) << 4)));
        xacc[dg] = mfma16(ap, bv, xacc[dg]);
      }
    }

    if (kt < NT - 1) {   // write staged regs into the other buffer
      char* nb = lds + ((kt + 1) & 1) * 16384;
      *(i32x4*)(nb + kd)        = kA;
      *(i32x4*)(nb + 8192 + kd) = vA;
    }
  }

  // ---- epilogue: combine key halves (reuse P region), mask, L2-norm, +=
  __syncthreads();
  float* cmb = (float*)(lds + 32768);
  if (kh == 1) {
    #pragma unroll
    for (int r = 0; r < 4; ++r)
      #pragma unroll
      for (int dg = 0; dg < 4; ++dg)
        cmb[qsub * 1024 + (hi * 4 + r) * 64 + dg * 16 + lo] = xacc[dg][r];
  }
  __syncthreads();
  if (kh == 0) {
    #pragma unroll
    for (int r = 0; r < 4; ++r) {
      int row = q0 + qsub * 16 + hi * 4 + r;
      float m = mask[b * NS + row];
      float vals[4];
      float ss = 0.f;
      #pragma unroll
      for (int dg = 0; dg < 4; ++dg) {
        float x = (xacc[dg][r] + cmb[qsub * 1024 + (hi * 4 + r) * 64 + dg * 16 + lo]) * m;
        vals[dg] = x;
        ss += x * x;
      }
      #pragma unroll
      for (int mm = 1; mm < 16; mm <<= 1) ss += __shfl_xor(ss, mm);
      float scale = rsqrtf(fmaxf(ss, 1e-24f));
      size_t base = ((size_t)bh * NS + row) * ND;
      #pragma unroll
      for (int dg = 0; dg < 4; ++dg)
        out[base + dg * 16 + lo] += vals[dg] * scale;
    }
  }
}

// ---------------------------------------------------------------------------
extern "C" void kernel_launch(void* const* d_in, const int* in_sizes, int n_in,
                              void* d_out, int out_size, void* d_ws, size_t ws_size,
                              hipStream_t stream) {
  const float* Q    = (const float*)d_in[0];
  const float* K    = (const float*)d_in[1];
  const float* V    = (const float*)d_in[2];
  const float* mask = (const float*)d_in[3];
  const float* cw   = (const float*)d_in[4];
  float* out = (float*)d_out;

  bf16* Kn  = (bf16*)d_ws;
  bf16* Vmt = Kn + (size_t)BHS * ND;

  prep<<<dim3(NS / 64, BH), 256, 0, stream>>>(K, V, mask, cw, out, Kn, Vmt);
  yoso_attn<<<(NS / 64) * BH, 512, 0, stream>>>(Q, Kn, Vmt, mask, out);
}